// Round 4
// baseline (310.319 us; speedup 1.0000x reference)
//
#include <hip/hip_runtime.h>
#include <stdint.h>

typedef float  v4f __attribute__((ext_vector_type(4)));
typedef short  v4s __attribute__((ext_vector_type(4)));
typedef int    v4i __attribute__((ext_vector_type(4)));

#define LOG2E 1.44269504088896340736f
#define LN2   0.69314718055994530942f

static __device__ __forceinline__ float fexp2(float x){ return __builtin_amdgcn_exp2f(x); }
static __device__ __forceinline__ float flog2(float x){ return __builtin_amdgcn_logf(x); }

// pack two f32 -> two bf16 (round-half-up) in one dword via v_perm
static __device__ __forceinline__ unsigned pkbf(float a, float b){
  unsigned ua = __float_as_uint(a) + 0x8000u;
  unsigned ub = __float_as_uint(b) + 0x8000u;
  return __builtin_amdgcn_perm(ub, ua, 0x07060302u);
}
static __device__ __forceinline__ v4s pack4(const v4f& m){
  union { unsigned u[2]; v4s s; } t;
  t.u[0] = pkbf(m.x, m.y);
  t.u[1] = pkbf(m.z, m.w);
  return t.s;
}

static __device__ __forceinline__ v4f mfma16(v4s a, v4s b, v4f c){
#if __has_builtin(__builtin_amdgcn_mfma_f32_16x16x16bf16_1k)
  return __builtin_amdgcn_mfma_f32_16x16x16bf16_1k(a, b, c, 0, 0, 0);
#else
  v4f r = c;
  asm("s_nop 1\n\tv_mfma_f32_16x16x16_bf16 %0, %1, %2, %0\n\ts_nop 7\n\ts_nop 1"
      : "+v"(r) : "v"(a), "v"(b));
  return r;
#endif
}

static __device__ __forceinline__ float sel4(const v4f& e4, int s){
  float a = (s & 1) ? e4.y : e4.x;
  float c = (s & 1) ? e4.w : e4.z;
  return (s & 2) ? c : a;
}

// ---------------- Phase 1 ----------------
// ILP-2: each wave carries TWO independent chains (8 (batch,chunk) pairs total),
// each chain = 4 pairs in one 16x16x16 bf16 MFMA (blockdiag(E^T,E^T) x 2x2 col-octets).
// Lane roles: n=lane&15, q=lane>>4, qr=q&1 (row half r0=4*qr), cn=n&7 (column),
// matrix mm=((q>>1)<<1)|(n>>3). Recurrence P' = diag(exp(em_t)) * E^T * P.
// D (C-layout) == next B (B-layout) -> zero-shuffle feedback.
// exp/numerator work distributed by step across 8 column lanes; exps broadcast via
// a wave-local LDS slot (per-wave DS ops are in-order: no barrier, single slot/chain).

template<bool MASKED>
__device__ __forceinline__ void chunk_loop2(
    const float* __restrict__ embA, const int* __restrict__ tgbA,
    const float* __restrict__ embB, const int* __restrict__ tgbB,
    int c, const float* s_trans, const float* s_end,
    float* slA, float* slB,
    v4s afrag, int qr, int r0, int cn, bool lastChunk,
    v4f& mA, v4s& bfA, float& lZA, float& numA,
    v4f& mB, v4s& bfB, float& lZB, float& numB)
{
  v4f eoA[2], eoB[2];
  v4i tA0[2], tA1[2], tB0[2], tB1[2];
  int tcA[2], tpA[2], tcB[2], tpB[2];

  auto loadK = [&](const float* __restrict__ emb, const int* __restrict__ tgb,
                   int kb, int par, v4f (&eo)[2], v4i (&g0)[2], v4i (&g1)[2],
                   int (&tc)[2], int (&tp)[2]){
    const int t0 = kb << 3;
    eo[par] = *(const v4f*)(emb + (size_t)(t0 + cn) * 8u);
    if (MASKED){
      g0[par] = *(const v4i*)(tgb + t0);
      g1[par] = *(const v4i*)(tgb + t0 + 4);
    }
    tc[par] = tgb[t0 + cn];
    int ip = t0 + cn - 1;
    if (!MASKED && c == 0 && ip < 0) ip = 0;   // global t=0: value unused
    tp[par] = tgb[ip];
  };

  auto numer = [&](const v4f& eo, int tc, int tp, bool sk0, float& num){
    bool act = MASKED ? (tc != 0) : true;
    if (sk0) act = false;
    const int s = tc - 1;
    const float ev = sel4(eo, s);
    num += (act && ((s >> 2) == qr)) ? ev : 0.f;
    const float tv = s_trans[(((tp - 1) & 7) << 3) + (s & 7)];
    num += (act && (qr == 0)) ? tv : 0.f;
    if (MASKED && (tp != 0) && (tc == 0) && (qr == 0)) num += s_end[tp - 1];
  };

  auto renorm = [&](v4f& m, v4s& bf, float& lZ){
    float mx = fmaxf(fmaxf(m.x, m.y), fmaxf(m.z, m.w));
    mx = fmaxf(mx, __shfl_xor(mx, 16, 64));   // column max across the qr pair
    const float inv = __builtin_amdgcn_rcpf(mx);
    m.x *= inv; m.y *= inv; m.z *= inv; m.w *= inv;
    lZ += flog2(mx);
    bf = pack4(m);
  };

  loadK(embA, tgbA, 0, 0, eoA, tA0, tA1, tcA, tpA);
  loadK(embB, tgbB, 0, 0, eoB, tB0, tB1, tcB, tpB);
  loadK(embA, tgbA, 1, 1, eoA, tA0, tA1, tcA, tpA);
  loadK(embB, tgbB, 1, 1, eoB, tB0, tB1, tcB, tpB);

#pragma unroll 2
  for (int kb = 0; kb < 8; ++kb){
    const int par = kb & 1;
    // prep: distributed exps -> LDS broadcast (this lane covers step kb*8+cn)
    v4f edA, edB;
    edA.x = fexp2(eoA[par].x * LOG2E); edA.y = fexp2(eoA[par].y * LOG2E);
    edA.z = fexp2(eoA[par].z * LOG2E); edA.w = fexp2(eoA[par].w * LOG2E);
    *(v4f*)(slA + (cn << 2)) = edA;
    edB.x = fexp2(eoB[par].x * LOG2E); edB.y = fexp2(eoB[par].y * LOG2E);
    edB.z = fexp2(eoB[par].z * LOG2E); edB.w = fexp2(eoB[par].w * LOG2E);
    *(v4f*)(slB + (cn << 2)) = edB;

    const bool sk0 = (!MASKED) && (c == 0) && (kb == 0);
    numer(eoA[par], tcA[par], tpA[par], sk0 && (cn == 0), numA);
    numer(eoB[par], tcB[par], tpB[par], sk0 && (cn == 0), numB);

    // snapshot mask vectors before the prefetch clobbers parity slot `par`
    v4i ma0, ma1, mb0, mb1;
    if (MASKED){ ma0 = tA0[par]; ma1 = tA1[par]; mb0 = tB0[par]; mb1 = tB1[par]; }

    if (kb + 2 < 8){
      loadK(embA, tgbA, kb + 2, par, eoA, tA0, tA1, tcA, tpA);
      loadK(embB, tgbB, kb + 2, par, eoB, tB0, tB1, tcB, tpB);
    }

    // 8 recurrence steps, two chains interleaved
#pragma unroll
    for (int j = 0; j < 8; ++j){
      v4f zero = {0.f, 0.f, 0.f, 0.f};
      v4f dA = mfma16(afrag, bfA, zero);
      v4f dB = mfma16(afrag, bfB, zero);
      v4f eA = *(const v4f*)(slA + (j << 2));
      v4f eB = *(const v4f*)(slB + (j << 2));
      if (!(sk0 && j == 0)){
        if (MASKED){
          const int ctA = (j < 4) ? ma0[j] : ma1[j - 4];
          const bool vA = (ctA != 0);
          mA.x = vA ? dA.x * eA.x : mA.x;
          mA.y = vA ? dA.y * eA.y : mA.y;
          mA.z = vA ? dA.z * eA.z : mA.z;
          mA.w = vA ? dA.w * eA.w : mA.w;
          const int ctB = (j < 4) ? mb0[j] : mb1[j - 4];
          const bool vB = (ctB != 0);
          mB.x = vB ? dB.x * eB.x : mB.x;
          mB.y = vB ? dB.y * eB.y : mB.y;
          mB.z = vB ? dB.z * eB.z : mB.z;
          mB.w = vB ? dB.w * eB.w : mB.w;
        } else {
          mA.x = dA.x * eA.x; mA.y = dA.y * eA.y; mA.z = dA.z * eA.z; mA.w = dA.w * eA.w;
          mB.x = dB.x * eB.x; mB.y = dB.y * eB.y; mB.z = dB.z * eB.z; mB.w = dB.w * eB.w;
        }
        bfA = pack4(mA);
        bfB = pack4(mB);
      }
    }

    if (par == 1){ renorm(mA, bfA, lZA); renorm(mB, bfB, lZB); }  // every 16 steps
  }

  if (MASKED && lastChunk){
    const int ltA = tgbA[63];
    if ((ltA != 0) && (qr == 0) && (cn == 0)) numA += s_end[ltA - 1];
    const int ltB = tgbB[63];
    if ((ltB != 0) && (qr == 0) && (cn == 0)) numB += s_end[ltB - 1];
  }
}

__global__ __launch_bounds__(256, 4)
void crf_phase1(const float* __restrict__ em,
                const float* __restrict__ trans,
                const float* __restrict__ endt,
                const int*   __restrict__ tags,
                float* __restrict__ ws)
{
  const int tid  = threadIdx.x;
  const int lane = tid & 63;
  const int n = lane & 15, q = lane >> 4, qr = q & 1, r0 = qr << 2, cn = n & 7;
  const int mm = ((q >> 1) << 1) | (n >> 3);
  const int pbase = (blockIdx.x << 5) + ((tid >> 6) << 3);   // 8 pairs per wave
  const int c   = pbase >> 11;                 // chunk id (uniform per block)
  const int bmA = (pbase & 2047) + mm;         // batch ids (no wrap: pbase&2047 <= 2040)
  const int bmB = (pbase & 2047) + 4 + mm;

  __shared__ float s_trans[64];
  __shared__ float s_end[8];
  __shared__ float s_e[32 * 72];               // 32 groups x (2 chains x 32 + 8 pad)
  if (tid < 64) s_trans[tid] = trans[tid];
  if (tid < 8)  s_end[tid]  = endt[tid];
  __syncthreads();

  // constant A fragment: blockdiag(E^T, E^T); A[m][k], m=n, k=4q+j
  v4s afrag;
  {
    float av[4];
#pragma unroll
    for (int j = 0; j < 4; ++j){
      const int k = (q << 2) + j;
      float v = 0.f;
      if (n < 8 && k < 8)        v = fexp2(s_trans[k * 8 + n] * LOG2E);
      else if (n >= 8 && k >= 8) v = fexp2(s_trans[(k - 8) * 8 + (n - 8)] * LOG2E);
      av[j] = v;
    }
    union { unsigned u[2]; v4s s; } t;
    t.u[0] = pkbf(av[0], av[1]);
    t.u[1] = pkbf(av[2], av[3]);
    afrag = t.s;
  }

  const float* embA = em   + ((size_t)bmA * 2048u + (size_t)c * 64u) * 8u + (unsigned)r0;
  const float* embB = em   + ((size_t)bmB * 2048u + (size_t)c * 64u) * 8u + (unsigned)r0;
  const int*   tgbA = tags + (size_t)bmA * 2048u + (size_t)c * 64u;
  const int*   tgbB = tags + (size_t)bmB * 2048u + (size_t)c * 64u;
  float* slA = &s_e[(tid >> 3) * 72];
  float* slB = slA + 32;

  // P = identity
  v4f mA, mB;
  mA.x = (r0 + 0 == cn) ? 1.f : 0.f;
  mA.y = (r0 + 1 == cn) ? 1.f : 0.f;
  mA.z = (r0 + 2 == cn) ? 1.f : 0.f;
  mA.w = (r0 + 3 == cn) ? 1.f : 0.f;
  mB = mA;
  v4s bfA = pack4(mA), bfB = pack4(mB);
  float numA = 0.f, lZA = 0.f, numB = 0.f, lZB = 0.f;

  if (c <= 15){                                // steps < 1024: never masked
    chunk_loop2<false>(embA, tgbA, embB, tgbB, c, s_trans, s_end, slA, slB,
                       afrag, qr, r0, cn, false,
                       mA, bfA, lZA, numA, mB, bfB, lZB, numB);
  } else {
    const bool fzA = (tgbA[0] == 0), fzB = (tgbB[0] == 0);
    if (__ballot(fzA && fzB) == ~0ull){        // all 8 pairs fully masked
      const int pvA = tgbA[-1];
      if ((pvA != 0) && (qr == 0) && (cn == 0)) numA = s_end[pvA - 1];
      const int pvB = tgbB[-1];
      if ((pvB != 0) && (qr == 0) && (cn == 0)) numB = s_end[pvB - 1];
      // masters stay identity, lZ stays 0
    } else {
      chunk_loop2<true>(embA, tgbA, embB, tgbB, c, s_trans, s_end, slA, slB,
                        afrag, qr, r0, cn, (c == 31),
                        mA, bfA, lZA, numA, mB, bfB, lZB, numB);
    }
  }

  // ---- store, [c][entry-pair][b] layout (phase-2 coalescing) ----
  auto storeC = [&](int bm, const v4f& m, float lZ, float num){
    float2* ws2 = ((float2*)ws) + (size_t)c * 40u * 2048u + (unsigned)bm;
    const int e0 = (cn << 3) + r0;             // entry e = col*8 + row (even)
    float2 v01; v01.x = m.x; v01.y = m.y;
    float2 v23; v23.x = m.z; v23.y = m.w;
    ws2[(size_t)(e0 >> 1) * 2048u]       = v01;
    ws2[(size_t)((e0 >> 1) + 1) * 2048u] = v23;
    if (qr == 0)
      ((float*)(ws2 + (size_t)((64 + cn) >> 1) * 2048u))[cn & 1] = lZ;
    float nt = num;
    nt += __shfl_xor(nt, 1, 64);
    nt += __shfl_xor(nt, 2, 64);
    nt += __shfl_xor(nt, 4, 64);
    nt += __shfl_xor(nt, 16, 64);
    if (qr == 0 && cn == 0)
      ((float*)(ws2 + (size_t)36 * 2048u))[0] = nt;
  };
  storeC(bmA, mA, lZA, numA);
  storeC(bmB, mB, lZB, numB);
}

// ---------------- Phase 2: per-batch combine of chunk matrices ----------------
// One thread per batch; single-buffered chunk load (no VGPR spill).
__global__ __launch_bounds__(64, 4)
void crf_phase2(const float* __restrict__ em,
                const float* __restrict__ strt,
                const float* __restrict__ endt,
                const int*   __restrict__ tags,
                const float* __restrict__ ws,
                float* __restrict__ out)
{
  const int lane = threadIdx.x;
  const int b = (blockIdx.x << 6) + lane;

  const float* em0 = em + (size_t)b * 16384u;
  float al[8];
#pragma unroll
  for (int i = 0; i < 8; ++i) al[i] = strt[i] + em0[i];
  const int s0 = tags[(size_t)b * 2048u] - 1;  // t=0 always valid (len >= 1024)
  float num = strt[s0] + em0[s0];

  float mx = al[0];
#pragma unroll
  for (int i = 1; i < 8; ++i) mx = fmaxf(mx, al[i]);
  float a[8];
#pragma unroll
  for (int i = 0; i < 8; ++i) a[i] = fexp2((al[i] - mx) * LOG2E);
  float lZ2 = mx * LOG2E;

#pragma unroll 1
  for (int cc = 0; cc < 32; ++cc){
    const float2* base = ((const float2*)ws) + (size_t)cc * 40u * 2048u + (unsigned)b;
    float P[64], ls[8];
#pragma unroll
    for (int i2 = 0; i2 < 32; ++i2){
      float2 v = base[(size_t)i2 * 2048u];
      P[2 * i2] = v.x; P[2 * i2 + 1] = v.y;
    }
#pragma unroll
    for (int k = 0; k < 4; ++k){
      float2 v = base[(size_t)(32 + k) * 2048u];
      ls[2 * k] = v.x; ls[2 * k + 1] = v.y;
    }
    const float nm = base[(size_t)36 * 2048u].x;

    float lm = ls[0];
#pragma unroll
    for (int i = 1; i < 8; ++i) lm = fmaxf(lm, ls[i]);
    float w[8];
#pragma unroll
    for (int i = 0; i < 8; ++i) w[i] = a[i] * fexp2(ls[i] - lm);
    float acc[8] = {0.f,0.f,0.f,0.f,0.f,0.f,0.f,0.f};
#pragma unroll
    for (int i = 0; i < 8; ++i)
#pragma unroll
      for (int j = 0; j < 8; ++j)
        acc[j] += w[i] * P[i * 8 + j];         // alpha'[row j] += w[col i] * P[col i][row j]
    float m2 = acc[0];
#pragma unroll
    for (int j = 1; j < 8; ++j) m2 = fmaxf(m2, acc[j]);
    const float inv = __builtin_amdgcn_rcpf(m2);
#pragma unroll
    for (int j = 0; j < 8; ++j) a[j] = acc[j] * inv;
    lZ2 += lm + flog2(m2);
    num += nm;
  }

  float accf = 0.f;
#pragma unroll
  for (int j = 0; j < 8; ++j) accf += a[j] * fexp2(endt[j] * LOG2E);
  const float denom = (flog2(accf) + lZ2) * LN2;
  float contrib = (denom - num) * (1.0f / 2048.0f);

#pragma unroll
  for (int off = 32; off; off >>= 1) contrib += __shfl_down(contrib, off, 64);
  if (lane == 0) atomicAdd(out, contrib);
}

extern "C" void kernel_launch(void* const* d_in, const int* in_sizes, int n_in,
                              void* d_out, int out_size, void* d_ws, size_t ws_size,
                              hipStream_t stream) {
  const float* em    = (const float*)d_in[0];
  const float* trans = (const float*)d_in[1];
  const float* strt  = (const float*)d_in[2];
  const float* endt  = (const float*)d_in[3];
  const int*   tags  = (const int*)d_in[4];
  float* out = (float*)d_out;

  hipMemsetAsync(out, 0, sizeof(float), stream);
  // C=32 chunks of S=64 steps; 65536 (b,c) pairs, 8 per wave -> 2048 blocks of 256
  crf_phase1<<<2048, 256, 0, stream>>>(em, trans, endt, tags, (float*)d_ws);
  crf_phase2<<<32, 64, 0, stream>>>(em, strt, endt, tags, (const float*)d_ws, out);
}

// Round 6
// 243.684 us; speedup vs baseline: 1.2734x; 1.2734x over previous
//
#include <hip/hip_runtime.h>
#include <stdint.h>

typedef float  v4f __attribute__((ext_vector_type(4)));
typedef short  v4s __attribute__((ext_vector_type(4)));
typedef int    v4i __attribute__((ext_vector_type(4)));

#define LOG2E 1.44269504088896340736f
#define LN2   0.69314718055994530942f

static __device__ __forceinline__ float fexp2(float x){ return __builtin_amdgcn_exp2f(x); }
static __device__ __forceinline__ float flog2(float x){ return __builtin_amdgcn_logf(x); }

// pack two f32 -> two bf16 (round-half-up) in one dword via v_perm — PROVEN in R1-R4.
// (R5's __builtin_amdgcn_cvt_pk_bf16_f32 produced NaN output; suspected bad lowering.)
static __device__ __forceinline__ unsigned pkbf(float a, float b){
  unsigned ua = __float_as_uint(a) + 0x8000u;
  unsigned ub = __float_as_uint(b) + 0x8000u;
  return __builtin_amdgcn_perm(ub, ua, 0x07060302u);
}
static __device__ __forceinline__ v4s pack4(const v4f& m){
  union { unsigned u[2]; v4s s; } t;
  t.u[0] = pkbf(m.x, m.y);
  t.u[1] = pkbf(m.z, m.w);
  return t.s;
}

static __device__ __forceinline__ v4f mfma16(v4s a, v4s b, v4f c){
#if __has_builtin(__builtin_amdgcn_mfma_f32_16x16x16bf16_1k)
  return __builtin_amdgcn_mfma_f32_16x16x16bf16_1k(a, b, c, 0, 0, 0);
#else
  v4f r = c;
  asm("s_nop 1\n\tv_mfma_f32_16x16x16_bf16 %0, %1, %2, %0\n\ts_nop 7\n\ts_nop 1"
      : "+v"(r) : "v"(a), "v"(b));
  return r;
#endif
}

static __device__ __forceinline__ float sel4(const v4f& e4, int s){
  float a = (s & 1) ? e4.y : e4.x;
  float c = (s & 1) ? e4.w : e4.z;
  return (s & 2) ? c : a;
}

// ---------------- Phase 1 ----------------
// One chain per wave: 4 (batch,chunk) 8x8 transfer-matrix products via one
// 16x16x16 bf16 MFMA (blockdiag(E^T,E^T), 2x2 column-octets).
// Lane roles: n=lane&15, q=lane>>4, qr=q&1 (row half r0=4*qr), cn=n&7 (column),
// matrix mm=((q>>1)<<1)|(n>>3). Recurrence P' = diag(exp(em_t)) * E^T * P.
// D (C-layout) == next B (B-layout) -> zero-shuffle feedback.
// Pipelining: em/tags prefetched 2 blocks ahead (3 buffers); exps for block kb+1
// computed+written to the LDS broadcast slot during block kb (full-block distance
// between ds_write and its ds_reads). Per-wave DS ops are in-order: no barrier.

template<bool MASKED>
__device__ __forceinline__ void chunk_loop(
    const float* __restrict__ emb, const int* __restrict__ tgb, int c,
    const float* s_trans, const float* s_end, float* s_slot,
    v4s afrag, int qr, int r0, int cn, bool lastChunk,
    v4f& master, v4s& bfrag, float& lZ, float& num)
{
  v4f eo[3]; v4i g0[3], g1[3]; int tc[3], tp[3];

  auto loadK = [&](int kb, int buf){
    const int t0 = kb << 3;
    eo[buf] = *(const v4f*)(emb + (size_t)(t0 + cn) * 8u);
    if (MASKED){
      g0[buf] = *(const v4i*)(tgb + t0);
      g1[buf] = *(const v4i*)(tgb + t0 + 4);
    }
    tc[buf] = tgb[t0 + cn];
    int ip = t0 + cn - 1;
    if (c == 0 && ip < 0) ip = 0;        // global t=0: value unused
    tp[buf] = tgb[ip];
  };

  auto expwrite = [&](const v4f& e, int par){
    v4f ed;
    ed.x = fexp2(e.x * LOG2E); ed.y = fexp2(e.y * LOG2E);
    ed.z = fexp2(e.z * LOG2E); ed.w = fexp2(e.w * LOG2E);
    *(v4f*)(s_slot + (par << 5) + (cn << 2)) = ed;   // ds_write_b128
  };

  loadK(0, 0); loadK(1, 1); loadK(2, 2);
  expwrite(eo[0], 0);

#pragma unroll
  for (int kb = 0; kb < 8; ++kb){
    const int buf = kb % 3;

    // broadcast exps for this block (written one block ago)
    v4f e8[8];
    const float* sl = s_slot + ((kb & 1) << 5);
#pragma unroll
    for (int j = 0; j < 8; ++j) e8[j] = *(const v4f*)(sl + (j << 2));

    // exps for next block -> other parity slot (distance = one full block)
    if (kb + 1 < 8) expwrite(eo[(kb + 1) % 3], (kb + 1) & 1);

    // distributed numerator for step t = kb*8 + cn
    const bool sk0 = (!MASKED) && (c == 0) && (kb == 0);
    {
      bool act = MASKED ? (tc[buf] != 0) : true;
      if (sk0 && cn == 0) act = false;
      const int s = tc[buf] - 1;
      const float ev = sel4(eo[buf], s);
      num += (act && ((s >> 2) == qr)) ? ev : 0.f;
      const float tv = s_trans[(((tp[buf] - 1) & 7) << 3) + (s & 7)];
      num += (act && (qr == 0)) ? tv : 0.f;
      if (MASKED && (tp[buf] != 0) && (tc[buf] == 0) && (qr == 0))
        num += s_end[tp[buf] - 1];
    }

    // snapshot masks before the deep prefetch clobbers this buffer
    v4i m0, m1;
    if (MASKED){ m0 = g0[buf]; m1 = g1[buf]; }
    if (kb + 3 < 8) loadK(kb + 3, buf);

    // 8 recurrence steps
#pragma unroll
    for (int j = 0; j < 8; ++j){
      if (sk0 && j == 0) continue;       // global t=0 handled in phase 2
      v4f zero = {0.f, 0.f, 0.f, 0.f};
      v4f d = mfma16(afrag, bfrag, zero);
      const v4f e = e8[j];
      if (MASKED){
        const int ct = (j < 4) ? m0[j] : m1[j - 4];
        const bool v = (ct != 0);
        master.x = v ? d.x * e.x : master.x;
        master.y = v ? d.y * e.y : master.y;
        master.z = v ? d.z * e.z : master.z;
        master.w = v ? d.w * e.w : master.w;
      } else {
        master.x = d.x * e.x; master.y = d.y * e.y;
        master.z = d.z * e.z; master.w = d.w * e.w;
      }
      bfrag = pack4(master);
    }

    if (kb & 1){                          // renorm every 16 steps
      float mx = fmaxf(fmaxf(master.x, master.y), fmaxf(master.z, master.w));
      mx = fmaxf(mx, __shfl_xor(mx, 16, 64));
      const float inv = __builtin_amdgcn_rcpf(mx);
      master.x *= inv; master.y *= inv; master.z *= inv; master.w *= inv;
      lZ += flog2(mx);
      bfrag = pack4(master);
    }
  }

  if (MASKED && lastChunk){
    const int lt = tgb[63];               // tag at global t = L-1
    if ((lt != 0) && (qr == 0) && (cn == 0)) num += s_end[lt - 1];
  }
}

__global__ __launch_bounds__(256, 4)
void crf_phase1(const float* __restrict__ em,
                const float* __restrict__ trans,
                const float* __restrict__ endt,
                const int*   __restrict__ tags,
                float* __restrict__ ws)
{
  const int tid  = threadIdx.x;
  const int lane = tid & 63;
  const int n = lane & 15, q = lane >> 4, qr = q & 1, r0 = qr << 2, cn = n & 7;
  const int mm = ((q >> 1) << 1) | (n >> 3);
  const int p  = (blockIdx.x << 4) + ((tid >> 6) << 2) + mm;
  const int c  = p >> 11;                 // chunk id (S=64, C=32)
  const int bm = p & 2047;                // batch id

  __shared__ float s_trans[64];
  __shared__ float s_end[8];
  __shared__ float s_e[32 * 68];          // 32 groups x (2 slots x 32 + 4 pad)
  if (tid < 64) s_trans[tid] = trans[tid];
  if (tid < 8)  s_end[tid]  = endt[tid];
  __syncthreads();

  // constant A fragment: blockdiag(E^T, E^T); A[m][k], m=n, k=4q+j
  v4s afrag;
  {
    float av[4];
#pragma unroll
    for (int j = 0; j < 4; ++j){
      const int k = (q << 2) + j;
      float v = 0.f;
      if (n < 8 && k < 8)        v = fexp2(s_trans[k * 8 + n] * LOG2E);
      else if (n >= 8 && k >= 8) v = fexp2(s_trans[(k - 8) * 8 + (n - 8)] * LOG2E);
      av[j] = v;
    }
    union { unsigned u[2]; v4s s; } t;
    t.u[0] = pkbf(av[0], av[1]);
    t.u[1] = pkbf(av[2], av[3]);
    afrag = t.s;
  }

  const float* emb = em   + ((size_t)bm * 2048u + (size_t)c * 64u) * 8u + (unsigned)r0;
  const int*   tgb = tags + (size_t)bm * 2048u + (size_t)c * 64u;
  float* s_slot = &s_e[(tid >> 3) * 68];

  // P = identity
  v4f master;
  master.x = (r0 + 0 == cn) ? 1.f : 0.f;
  master.y = (r0 + 1 == cn) ? 1.f : 0.f;
  master.z = (r0 + 2 == cn) ? 1.f : 0.f;
  master.w = (r0 + 3 == cn) ? 1.f : 0.f;
  v4s bfrag = pack4(master);
  float num = 0.f, lZ = 0.f;

  if (c <= 15){                            // steps < 1024: never masked
    chunk_loop<false>(emb, tgb, c, s_trans, s_end, s_slot,
                      afrag, qr, r0, cn, false, master, bfrag, lZ, num);
  } else {
    const bool fz = (tgb[0] == 0);
    if (__ballot(fz) == ~0ull){            // all 4 pairs fully masked: identity
      const int pv = tgb[-1];
      if ((pv != 0) && (qr == 0) && (cn == 0)) num = s_end[pv - 1];
    } else {
      chunk_loop<true>(emb, tgb, c, s_trans, s_end, s_slot,
                       afrag, qr, r0, cn, (c == 31), master, bfrag, lZ, num);
    }
  }

  // ---- store, [c][entry-pair][b] layout (phase-2 coalescing) ----
  float2* ws2 = ((float2*)ws) + (size_t)c * 40u * 2048u + (unsigned)bm;
  const int e0 = (cn << 3) + r0;           // entry e = col*8 + row (even)
  float2 v01; v01.x = master.x; v01.y = master.y;
  float2 v23; v23.x = master.z; v23.y = master.w;
  ws2[(size_t)(e0 >> 1) * 2048u]       = v01;
  ws2[(size_t)((e0 >> 1) + 1) * 2048u] = v23;
  if (qr == 0)
    ((float*)(ws2 + (size_t)((64 + cn) >> 1) * 2048u))[cn & 1] = lZ;
  num += __shfl_xor(num, 1, 64);
  num += __shfl_xor(num, 2, 64);
  num += __shfl_xor(num, 4, 64);
  num += __shfl_xor(num, 16, 64);
  if (qr == 0 && cn == 0)
    ((float*)(ws2 + (size_t)36 * 2048u))[0] = num;
}

// ---------------- Phase 2: per-batch combine of chunk matrices ----------------
// 8 lanes per batch (lane j holds alpha[row j]); 16384 threads = 256 waves.
// Per chunk: ~10 scalar loads/lane, 3-chunk-deep rotating prefetch (<=30
// outstanding loads, under the vmcnt limit that broke the R3 version).
__global__ __launch_bounds__(256, 4)
void crf_phase2(const float* __restrict__ em,
                const float* __restrict__ strt,
                const float* __restrict__ endt,
                const int*   __restrict__ tags,
                const float* __restrict__ ws,
                float* __restrict__ out)
{
  const int tid  = threadIdx.x;
  const int lane = tid & 63;
  const int gt = (blockIdx.x << 8) + tid;
  const int b = gt >> 3;                   // batch
  const int j = gt & 7;                    // alpha row
  const int gbase = lane & 56;             // first lane of this batch's group

  // per-lane float offsets into ws
  const unsigned poff = ((unsigned)(j >> 1) << 12) + (unsigned)(j & 1) + ((unsigned)b << 1);
  const float* wsf = ws;

  // alpha0 and numerator t=0 term
  const float al = strt[j] + em[(size_t)b * 16384u + (unsigned)j];
  const int s0 = tags[(size_t)b * 2048u] - 1;       // t=0 always valid
  float num = __shfl(al, gbase + s0, 64);           // strt[s0] + em0[s0]

  float mx = al;
  mx = fmaxf(mx, __shfl_xor(mx, 1, 64));
  mx = fmaxf(mx, __shfl_xor(mx, 2, 64));
  mx = fmaxf(mx, __shfl_xor(mx, 4, 64));
  float a = fexp2((al - mx) * LOG2E);
  float lZ2 = mx * LOG2E;

  float Pb[4][8], lsb[4], nmb[4];
  auto loadChunk = [&](int c, int s){
    const float* base = wsf + (size_t)c * 163840u;
#pragma unroll
    for (int i = 0; i < 8; ++i) Pb[s][i] = base[poff + (unsigned)i * 16384u];
    lsb[s] = base[131072u + poff];
    nmb[s] = base[147456u + ((unsigned)b << 1)];
  };

  loadChunk(0, 0); loadChunk(1, 1); loadChunk(2, 2);

#pragma unroll 4
  for (int c = 0; c < 32; ++c){
    const int s = c & 3;
    if (c + 3 < 32) loadChunk(c + 3, (c + 3) & 3);

    // group max of column scales
    float ls = lsb[s];
    float lm = ls;
    lm = fmaxf(lm, __shfl_xor(lm, 1, 64));
    lm = fmaxf(lm, __shfl_xor(lm, 2, 64));
    lm = fmaxf(lm, __shfl_xor(lm, 4, 64));
    const float w = a * fexp2(ls - lm);

    // alpha'[j] = sum_i w_i * P[col i][row j]
    float acc = 0.f;
#pragma unroll
    for (int i = 0; i < 8; ++i)
      acc += __shfl(w, gbase + i, 64) * Pb[s][i];

    float m2 = acc;
    m2 = fmaxf(m2, __shfl_xor(m2, 1, 64));
    m2 = fmaxf(m2, __shfl_xor(m2, 2, 64));
    m2 = fmaxf(m2, __shfl_xor(m2, 4, 64));
    a = acc * __builtin_amdgcn_rcpf(m2);
    lZ2 += lm + flog2(m2);
    num += nmb[s];
  }

  // denominator
  float t = a * fexp2(endt[j] * LOG2E);
  t += __shfl_xor(t, 1, 64);
  t += __shfl_xor(t, 2, 64);
  t += __shfl_xor(t, 4, 64);
  const float denom = (flog2(t) + lZ2) * LN2;

  float contrib = (j == 0) ? (denom - num) * (1.0f / 2048.0f) : 0.f;
  contrib += __shfl_xor(contrib, 8, 64);
  contrib += __shfl_xor(contrib, 16, 64);
  contrib += __shfl_xor(contrib, 32, 64);
  if (lane == 0) atomicAdd(out, contrib);
}

extern "C" void kernel_launch(void* const* d_in, const int* in_sizes, int n_in,
                              void* d_out, int out_size, void* d_ws, size_t ws_size,
                              hipStream_t stream) {
  const float* em    = (const float*)d_in[0];
  const float* trans = (const float*)d_in[1];
  const float* strt  = (const float*)d_in[2];
  const float* endt  = (const float*)d_in[3];
  const int*   tags  = (const int*)d_in[4];
  float* out = (float*)d_out;

  hipMemsetAsync(out, 0, sizeof(float), stream);
  // C=32 chunks of S=64 steps; 65536 (b,c) pairs, 4 per wave -> 4096 blocks of 256
  crf_phase1<<<4096, 256, 0, stream>>>(em, trans, endt, tags, (float*)d_ws);
  crf_phase2<<<64, 256, 0, stream>>>(em, strt, endt, tags, (const float*)d_ws, out);
}